// Round 3
// baseline (165.033 us; speedup 1.0000x reference)
//
#include <hip/hip_runtime.h>
#include <math.h>

#define N_T   2000
#define NG    500     // float4 groups per trial
#define WAVES 4       // waves (=trials) per 256-thread block

// One wave per trial, STRIDED layout: lane i owns float4 group j*64+i, so
// every global load/store is 1KB-contiguous per wave64 instruction with NO
// transpose. The linear recurrence e[t]=decay*e[t-1]+u[t-1] is solved in
// closed form: e[t] = decay^t * (sp + S[t]), S[t] = sum_{k<t} u[k]*invd^(k+1).
// decay^±2000 ∈ [0.980,1.021], so the rescaling is numerically benign and the
// affine scan degenerates to a plain prefix sum: per 256-step block, a local
// 4-element prefix + one 6-step __shfl_up wave scan + a carry broadcast.
// Zero LDS, zero barriers; loads/stores interleave across the whole kernel.
__global__ __launch_bounds__(256) void ddm_kernel(
    const float* __restrict__ stim,
    const float* __restrict__ noise,
    const float* __restrict__ a_p,
    const float* __restrict__ z_p,
    const float* __restrict__ gain_p,
    const float* __restrict__ off_p,
    const float* __restrict__ beta_p,
    float* __restrict__ out,
    int n_trials)
{
    const int wave  = threadIdx.x >> 6;
    const int lane  = threadIdx.x & 63;
    const int trial = blockIdx.x * WAVES + wave;
    if (trial >= n_trials) return;

    constexpr float DT   = 0.001f;
    constexpr float LEAK = 0.01f;
    constexpr float DEC  = 1.0f - LEAK * DT;          // 0.99999
    constexpr float INV  = 1.0f / DEC;
    constexpr float De2 = DEC * DEC, De3 = De2 * DEC, De4 = De2 * De2;
    constexpr float I2  = INV * INV, I3  = I2 * INV, I4  = I2 * I2;
    constexpr float D8 = De4 * De4, D16 = D8 * D8, D32 = D16 * D16,
                    D64 = D32 * D32, D128 = D64 * D64, D256 = D128 * D128;
    constexpr float I8 = I4 * I4, I16 = I8 * I8, I32 = I16 * I16,
                    I64 = I32 * I32, I128 = I64 * I64, I256 = I128 * I128;

    const float a    = *a_p;
    const float z    = *z_p;
    const float gain = *gain_p;
    const float offs = *off_p;
    const float beta = *beta_p;

    const float sp = z * a;
    const float C1 = gain * DT;
    const float C2 = sqrtf(1.0f * DT);                // sqrt(VARIANCE*DT)
    const float C3 = offs * DT + LEAK * sp * DT;

    // per-lane powers: dl = DEC^(4*lane), il = INV^(4*lane+1)  (binary powering)
    float dl = 1.f, il = 1.f, bd = De4, bi = I4;
    int nb = lane;
#pragma unroll
    for (int b = 0; b < 6; ++b) {
        if (nb & 1) { dl *= bd; il *= bi; }
        bd *= bd; bi *= bi; nb >>= 1;
    }
    il *= INV;

    const float* srow = stim  + (size_t)trial * N_T;
    const float* nrow = noise + (size_t)trial * N_T;
    float* dv_out = out;
    float* h1_out = out + (size_t)n_trials * N_T;
    float* h0_out = out + 2 * (size_t)n_trials * N_T;
    const size_t rbase = (size_t)trial * N_T;

    float carry = 0.f;       // prefix sum of w over all previous blocks
    float dpj = dl;          // DEC^(4*lane) * DEC^(256*j)
    float ifj = il;          // INV^(4*lane+1) * INV^(256*j)

    // prefetch j=0 (all 64 groups valid: 64 < 500)
    float4 s_cur = *(const float4*)(srow + 4 * lane);
    float4 n_cur = *(const float4*)(nrow + 4 * lane);

#pragma unroll
    for (int j = 0; j < 8; ++j) {
        float4 s_nxt = make_float4(0.f, 0.f, 0.f, 0.f);
        float4 n_nxt = make_float4(0.f, 0.f, 0.f, 0.f);
        if (j < 7) {
            const int g2 = (j + 1) * 64 + lane;
            if (g2 < NG) {
                s_nxt = *(const float4*)(srow + 4 * g2);
                n_nxt = *(const float4*)(nrow + 4 * g2);
            }
        }

        const int  g     = j * 64 + lane;
        const bool valid = g < NG;                    // only j==7 partial
        const float m    = valid ? 1.f : 0.f;
        const int  t0    = 4 * g;

        const float u0 = C1 * s_cur.x + C2 * n_cur.x + C3;
        const float u1 = C1 * s_cur.y + C2 * n_cur.y + C3;
        const float u2 = C1 * s_cur.z + C2 * n_cur.z + C3;
        const float u3 = C1 * s_cur.w + C2 * n_cur.w + C3;

        const float w0 = u0 * ifj * m;
        const float w1 = u1 * (ifj * INV) * m;
        const float w2 = u2 * (ifj * I2) * m;
        const float w3 = u3 * (ifj * I3) * m;

        const float l0 = w0, l1 = l0 + w1, l2 = l1 + w2, l3 = l2 + w3;

        // inclusive wave scan of lane totals
        float sc = l3;
#pragma unroll
        for (int off = 1; off < 64; off <<= 1) {
            const float v = __shfl_up(sc, off, 64);
            sc += (lane >= off) ? v : 0.f;
        }
        const float excl = sc - l3;
        const float btot = __shfl(sc, 63, 64);
        const float S0   = carry + excl;
        carry += btot;

        // e[t] = DEC^t * (sp + S[t])
        const float e0 = dpj *         (sp + S0);
        const float e1 = (dpj * DEC) * (sp + S0 + l0);
        const float e2 = (dpj * De2) * (sp + S0 + l1);
        const float e3 = (dpj * De3) * (sp + S0 + l2);

        float4 dv4, h14, h04;
        dv4.x = (float)(t0    ) * 0.01f * (e0 - sp) + sp;
        dv4.y = (float)(t0 + 1) * 0.01f * (e1 - sp) + sp;
        dv4.z = (float)(t0 + 2) * 0.01f * (e2 - sp) + sp;
        dv4.w = (float)(t0 + 3) * 0.01f * (e3 - sp) + sp;
#pragma unroll
        for (int q = 0; q < 4; ++q) {
            const float dv = ((const float*)&dv4)[q];
            ((float*)&h14)[q] = __builtin_amdgcn_rcpf(1.0f + __expf(-beta * (dv - a)));
            ((float*)&h04)[q] = __builtin_amdgcn_rcpf(1.0f + __expf( beta * dv));
        }

        if (valid) {
            const size_t base = rbase + (size_t)t0;
            *(float4*)(dv_out + base) = dv4;
            *(float4*)(h1_out + base) = h14;
            *(float4*)(h0_out + base) = h04;
        }

        dpj *= D256;
        ifj *= I256;
        s_cur = s_nxt;
        n_cur = n_nxt;
    }
}

extern "C" void kernel_launch(void* const* d_in, const int* in_sizes, int n_in,
                              void* d_out, int out_size, void* d_ws, size_t ws_size,
                              hipStream_t stream) {
    const float* stim  = (const float*)d_in[0];
    const float* noise = (const float*)d_in[1];
    const float* a_p   = (const float*)d_in[2];
    const float* z_p   = (const float*)d_in[3];
    const float* g_p   = (const float*)d_in[4];
    const float* o_p   = (const float*)d_in[5];
    const float* b_p   = (const float*)d_in[6];
    float* outp = (float*)d_out;

    const int n_trials = in_sizes[0] / N_T;
    const int blocks = (n_trials + WAVES - 1) / WAVES;
    ddm_kernel<<<blocks, 256, 0, stream>>>(stim, noise, a_p, z_p, g_p, o_p, b_p,
                                           outp, n_trials);
}

// Round 4
// 162.601 us; speedup vs baseline: 1.0150x; 1.0150x over previous
//
#include <hip/hip_runtime.h>
#include <math.h>

#define N_T   2000
#define NG    500     // float4 groups per trial
#define WAVES 4       // waves (=trials) per 256-thread block

// One wave per trial, strided layout (lane i owns float4 group j*64+i):
// every global access is 1KB-contiguous per wave64 instruction.
// Closed form for the recurrence: e[t] = DEC^t * (sp + S[t]),
// S[t] = sum_{k<t} u[k]*INV^(k+1)  -> plain prefix sum.
// Latency-focused structure:
//   (1) ALL 16 global loads issued up front (max MLP),
//   (2) per-j lane prefix quads,
//   (3) 8 wave-scans interleaved step-synchronously (shuffles pipeline),
//   (4) per-lane carry composition (no extra shuffle chain),
//   (5) outputs. Zero LDS, zero barriers.
__global__ __launch_bounds__(256, 4) void ddm_kernel(
    const float* __restrict__ stim,
    const float* __restrict__ noise,
    const float* __restrict__ a_p,
    const float* __restrict__ z_p,
    const float* __restrict__ gain_p,
    const float* __restrict__ off_p,
    const float* __restrict__ beta_p,
    float* __restrict__ out,
    int n_trials)
{
    const int wave  = threadIdx.x >> 6;
    const int lane  = threadIdx.x & 63;
    const int trial = blockIdx.x * WAVES + wave;
    if (trial >= n_trials) return;

    constexpr float DT   = 0.001f;
    constexpr float LEAK = 0.01f;
    constexpr float DEC  = 1.0f - LEAK * DT;          // 0.99999
    constexpr float INV  = 1.0f / DEC;
    constexpr float De2 = DEC * DEC, De3 = De2 * DEC, De4 = De2 * De2;
    constexpr float I2  = INV * INV, I3  = I2 * INV, I4  = I2 * I2;
    constexpr float D8 = De4 * De4, D16 = D8 * D8, D32 = D16 * D16,
                    D64 = D32 * D32, D128 = D64 * D64, D256 = D128 * D128;
    constexpr float I8 = I4 * I4, I16 = I8 * I8, I32 = I16 * I16,
                    I64 = I32 * I32, I128 = I64 * I64, I256 = I128 * I128;

    const float a    = *a_p;
    const float z    = *z_p;
    const float gain = *gain_p;
    const float offs = *off_p;
    const float beta = *beta_p;

    const float sp = z * a;
    const float C1 = gain * DT;
    const float C2 = sqrtf(1.0f * DT);                // sqrt(VARIANCE*DT)
    const float C3 = offs * DT + LEAK * sp * DT;

    // per-lane base powers: dl = DEC^(4*lane), il = INV^(4*lane+1)
    float dl = 1.f, il = 1.f, bd = De4, bi = I4;
    int nb = lane;
#pragma unroll
    for (int b = 0; b < 6; ++b) {
        if (nb & 1) { dl *= bd; il *= bi; }
        bd *= bd; bi *= bi; nb >>= 1;
    }
    il *= INV;

    const float* srow = stim  + (size_t)trial * N_T;
    const float* nrow = noise + (size_t)trial * N_T;

    // ---- (1) all loads up front; clamp OOB lanes (j==7, lane>=52) ----
    float4 sv[8], nv[8];
#pragma unroll
    for (int j = 0; j < 8; ++j) {
        const int g  = j * 64 + lane;
        const int gc = (g < NG) ? g : (NG - 1);
        sv[j] = *(const float4*)(srow + 4 * gc);
        nv[j] = *(const float4*)(nrow + 4 * gc);
    }

    // ---- (2) per-j lane prefix quads ----
    float l0[8], l1[8], l2[8], l3[8];
    {
        float ifj = il;
#pragma unroll
        for (int j = 0; j < 8; ++j) {
            const float m = ((j * 64 + lane) < NG) ? 1.f : 0.f;
            const float u0 = C1 * sv[j].x + C2 * nv[j].x + C3;
            const float u1 = C1 * sv[j].y + C2 * nv[j].y + C3;
            const float u2 = C1 * sv[j].z + C2 * nv[j].z + C3;
            const float u3 = C1 * sv[j].w + C2 * nv[j].w + C3;
            const float w0 = u0 * ifj * m;
            const float w1 = u1 * (ifj * INV) * m;
            const float w2 = u2 * (ifj * I2) * m;
            const float w3 = u3 * (ifj * I3) * m;
            l0[j] = w0;
            l1[j] = l0[j] + w1;
            l2[j] = l1[j] + w2;
            l3[j] = l2[j] + w3;
            ifj *= I256;
        }
    }

    // ---- (3) 8 independent wave scans, step-synchronous (ILP) ----
    float sc[8];
#pragma unroll
    for (int j = 0; j < 8; ++j) sc[j] = l3[j];
#pragma unroll
    for (int off = 1; off < 64; off <<= 1) {
        float v[8];
#pragma unroll
        for (int j = 0; j < 8; ++j) v[j] = __shfl_up(sc[j], off, 64);
#pragma unroll
        for (int j = 0; j < 8; ++j) sc[j] += (lane >= off) ? v[j] : 0.f;
    }

    // ---- (4) carry composition (per-lane scalar, identical in all lanes) ----
    float S0[8];
    {
        float c = 0.f;
#pragma unroll
        for (int j = 0; j < 8; ++j) {
            const float btot = __shfl(sc[j], 63, 64);
            S0[j] = c + (sc[j] - l3[j]);
            c += btot;
        }
    }

    // ---- (5) outputs ----
    float* dv_out = out;
    float* h1_out = out + (size_t)n_trials * N_T;
    float* h0_out = out + 2 * (size_t)n_trials * N_T;
    const size_t rbase = (size_t)trial * N_T;

    float dpj = dl;
#pragma unroll
    for (int j = 0; j < 8; ++j) {
        const int  g     = j * 64 + lane;
        const bool valid = g < NG;
        const int  t0    = 4 * g;

        const float e0 = dpj *         (sp + S0[j]);
        const float e1 = (dpj * DEC) * (sp + S0[j] + l0[j]);
        const float e2 = (dpj * De2) * (sp + S0[j] + l1[j]);
        const float e3 = (dpj * De3) * (sp + S0[j] + l2[j]);

        float4 dv4, h14, h04;
        dv4.x = (float)(t0    ) * 0.01f * (e0 - sp) + sp;
        dv4.y = (float)(t0 + 1) * 0.01f * (e1 - sp) + sp;
        dv4.z = (float)(t0 + 2) * 0.01f * (e2 - sp) + sp;
        dv4.w = (float)(t0 + 3) * 0.01f * (e3 - sp) + sp;
#pragma unroll
        for (int q = 0; q < 4; ++q) {
            const float dv = ((const float*)&dv4)[q];
            ((float*)&h14)[q] = __builtin_amdgcn_rcpf(1.0f + __expf(-beta * (dv - a)));
            ((float*)&h04)[q] = __builtin_amdgcn_rcpf(1.0f + __expf( beta * dv));
        }

        if (valid) {
            const size_t base = rbase + (size_t)t0;
            *(float4*)(dv_out + base) = dv4;
            *(float4*)(h1_out + base) = h14;
            *(float4*)(h0_out + base) = h04;
        }
        dpj *= D256;
    }
}

extern "C" void kernel_launch(void* const* d_in, const int* in_sizes, int n_in,
                              void* d_out, int out_size, void* d_ws, size_t ws_size,
                              hipStream_t stream) {
    const float* stim  = (const float*)d_in[0];
    const float* noise = (const float*)d_in[1];
    const float* a_p   = (const float*)d_in[2];
    const float* z_p   = (const float*)d_in[3];
    const float* g_p   = (const float*)d_in[4];
    const float* o_p   = (const float*)d_in[5];
    const float* b_p   = (const float*)d_in[6];
    float* outp = (float*)d_out;

    const int n_trials = in_sizes[0] / N_T;
    const int blocks = (n_trials + WAVES - 1) / WAVES;
    ddm_kernel<<<blocks, 256, 0, stream>>>(stim, noise, a_p, z_p, g_p, o_p, b_p,
                                           outp, n_trials);
}

// Round 6
// 157.676 us; speedup vs baseline: 1.0467x; 1.0312x over previous
//
#include <hip/hip_runtime.h>
#include <math.h>

#define N_T   2000
#define NG    500     // float4 groups per trial
#define WAVES 4       // waves (=trials) per 256-thread block

typedef float vf4 __attribute__((ext_vector_type(4)));   // native vector for nt builtins

// One wave per trial, strided layout (lane i owns float4 group j*64+i):
// every global access is 1KB-contiguous per wave64 instruction.
// Closed form: e[t] = DEC^t * (sp + S[t]), S[t] = sum_{k<t} u[k]*INV^(k+1)
// -> plain prefix sum (DEC^±2000 ∈ [0.98,1.02], numerically benign).
// All global traffic uses NONTEMPORAL (nt, no-allocate) loads/stores so the
// kernel's 164 MB stream doesn't churn L2/L3 (the harness's 393 MB poison
// fill leaves L3 full of dirty lines whose spill competes with us).
__global__ __launch_bounds__(256, 4) void ddm_kernel(
    const float* __restrict__ stim,
    const float* __restrict__ noise,
    const float* __restrict__ a_p,
    const float* __restrict__ z_p,
    const float* __restrict__ gain_p,
    const float* __restrict__ off_p,
    const float* __restrict__ beta_p,
    float* __restrict__ out,
    int n_trials)
{
    const int wave  = threadIdx.x >> 6;
    const int lane  = threadIdx.x & 63;
    const int trial = blockIdx.x * WAVES + wave;
    if (trial >= n_trials) return;

    constexpr float DT   = 0.001f;
    constexpr float LEAK = 0.01f;
    constexpr float DEC  = 1.0f - LEAK * DT;          // 0.99999
    constexpr float INV  = 1.0f / DEC;
    constexpr float De2 = DEC * DEC, De3 = De2 * DEC, De4 = De2 * De2;
    constexpr float I2  = INV * INV, I3  = I2 * INV, I4  = I2 * I2;
    constexpr float D8 = De4 * De4, D16 = D8 * D8, D32 = D16 * D16,
                    D64 = D32 * D32, D128 = D64 * D64, D256 = D128 * D128;
    constexpr float I8 = I4 * I4, I16 = I8 * I8, I32 = I16 * I16,
                    I64 = I32 * I32, I128 = I64 * I64, I256 = I128 * I128;

    const float a    = *a_p;
    const float z    = *z_p;
    const float gain = *gain_p;
    const float offs = *off_p;
    const float beta = *beta_p;

    const float sp = z * a;
    const float C1 = gain * DT;
    const float C2 = sqrtf(1.0f * DT);                // sqrt(VARIANCE*DT)
    const float C3 = offs * DT + LEAK * sp * DT;

    // per-lane base powers: dl = DEC^(4*lane), il = INV^(4*lane+1)
    float dl = 1.f, il = 1.f, bd = De4, bi = I4;
    int nb = lane;
#pragma unroll
    for (int b = 0; b < 6; ++b) {
        if (nb & 1) { dl *= bd; il *= bi; }
        bd *= bd; bi *= bi; nb >>= 1;
    }
    il *= INV;

    const float* srow = stim  + (size_t)trial * N_T;
    const float* nrow = noise + (size_t)trial * N_T;

    // ---- (1) all loads up front, nontemporal; clamp OOB (j==7, lane>=52) ----
    vf4 sv[8], nv[8];
#pragma unroll
    for (int j = 0; j < 8; ++j) {
        const int g  = j * 64 + lane;
        const int gc = (g < NG) ? g : (NG - 1);
        sv[j] = __builtin_nontemporal_load((const vf4*)(srow + 4 * gc));
        nv[j] = __builtin_nontemporal_load((const vf4*)(nrow + 4 * gc));
    }

    // ---- (2) per-j lane prefix quads ----
    float l0[8], l1[8], l2[8], l3[8];
    {
        float ifj = il;
#pragma unroll
        for (int j = 0; j < 8; ++j) {
            const float m = ((j * 64 + lane) < NG) ? 1.f : 0.f;
            const float u0 = C1 * sv[j].x + C2 * nv[j].x + C3;
            const float u1 = C1 * sv[j].y + C2 * nv[j].y + C3;
            const float u2 = C1 * sv[j].z + C2 * nv[j].z + C3;
            const float u3 = C1 * sv[j].w + C2 * nv[j].w + C3;
            const float w0 = u0 * ifj * m;
            const float w1 = u1 * (ifj * INV) * m;
            const float w2 = u2 * (ifj * I2) * m;
            const float w3 = u3 * (ifj * I3) * m;
            l0[j] = w0;
            l1[j] = l0[j] + w1;
            l2[j] = l1[j] + w2;
            l3[j] = l2[j] + w3;
            ifj *= I256;
        }
    }

    // ---- (3) 8 independent wave scans, step-synchronous (shuffles pipeline) ----
    float sc[8];
#pragma unroll
    for (int j = 0; j < 8; ++j) sc[j] = l3[j];
#pragma unroll
    for (int off = 1; off < 64; off <<= 1) {
        float v[8];
#pragma unroll
        for (int j = 0; j < 8; ++j) v[j] = __shfl_up(sc[j], off, 64);
#pragma unroll
        for (int j = 0; j < 8; ++j) sc[j] += (lane >= off) ? v[j] : 0.f;
    }

    // ---- (4) carry composition (per-lane scalar) ----
    float S0[8];
    {
        float c = 0.f;
#pragma unroll
        for (int j = 0; j < 8; ++j) {
            const float btot = __shfl(sc[j], 63, 64);
            S0[j] = c + (sc[j] - l3[j]);
            c += btot;
        }
    }

    // ---- (5) outputs, nontemporal stores ----
    float* dv_out = out;
    float* h1_out = out + (size_t)n_trials * N_T;
    float* h0_out = out + 2 * (size_t)n_trials * N_T;
    const size_t rbase = (size_t)trial * N_T;

    float dpj = dl;
#pragma unroll
    for (int j = 0; j < 8; ++j) {
        const int  g     = j * 64 + lane;
        const bool valid = g < NG;
        const int  t0    = 4 * g;

        const float e0 = dpj *         (sp + S0[j]);
        const float e1 = (dpj * DEC) * (sp + S0[j] + l0[j]);
        const float e2 = (dpj * De2) * (sp + S0[j] + l1[j]);
        const float e3 = (dpj * De3) * (sp + S0[j] + l2[j]);

        vf4 dv4, h14, h04;
        dv4.x = (float)(t0    ) * 0.01f * (e0 - sp) + sp;
        dv4.y = (float)(t0 + 1) * 0.01f * (e1 - sp) + sp;
        dv4.z = (float)(t0 + 2) * 0.01f * (e2 - sp) + sp;
        dv4.w = (float)(t0 + 3) * 0.01f * (e3 - sp) + sp;
#pragma unroll
        for (int q = 0; q < 4; ++q) {
            const float dv = dv4[q];
            h14[q] = __builtin_amdgcn_rcpf(1.0f + __expf(-beta * (dv - a)));
            h04[q] = __builtin_amdgcn_rcpf(1.0f + __expf( beta * dv));
        }

        if (valid) {
            const size_t base = rbase + (size_t)t0;
            __builtin_nontemporal_store(dv4, (vf4*)(dv_out + base));
            __builtin_nontemporal_store(h14, (vf4*)(h1_out + base));
            __builtin_nontemporal_store(h04, (vf4*)(h0_out + base));
        }
        dpj *= D256;
    }
}

extern "C" void kernel_launch(void* const* d_in, const int* in_sizes, int n_in,
                              void* d_out, int out_size, void* d_ws, size_t ws_size,
                              hipStream_t stream) {
    const float* stim  = (const float*)d_in[0];
    const float* noise = (const float*)d_in[1];
    const float* a_p   = (const float*)d_in[2];
    const float* z_p   = (const float*)d_in[3];
    const float* g_p   = (const float*)d_in[4];
    const float* o_p   = (const float*)d_in[5];
    const float* b_p   = (const float*)d_in[6];
    float* outp = (float*)d_out;

    const int n_trials = in_sizes[0] / N_T;
    const int blocks = (n_trials + WAVES - 1) / WAVES;
    ddm_kernel<<<blocks, 256, 0, stream>>>(stim, noise, a_p, z_p, g_p, o_p, b_p,
                                           outp, n_trials);
}